// Round 1
// baseline (216.265 us; speedup 1.0000x reference)
//
#include <hip/hip_runtime.h>
#include <hip/hip_bf16.h>

#define BB 2
#define CC 64
#define HWHW 65536   // 256*256
#define PEPE 128

typedef __attribute__((ext_vector_type(8))) short short8;
typedef __attribute__((ext_vector_type(4))) float f32x4;

__device__ __forceinline__ short f2bf(float f) {
  union { __hip_bfloat16 h; short s; } u;
  u.h = __float2bfloat16(f);
  return u.s;
}

// LDS budget (bytes):
//   union region [0, 150528): phase A = weight fragments (49152 B bf16)
//                             phase B = q/k/v fp32 staging (150528 B)
//   pos_bias fp32[4][128]  @ 150528 (2048 B)
//   biases   fp32[192]     @ 152576 (768 B)
//   total 153344 B  -> 1 block/CU (fine; VGPR-heavy by design)

__global__ __launch_bounds__(256, 1)
void iw_kernel(const float* __restrict__ feat_supp, const float* __restrict__ flow,
               const float* __restrict__ feat_curr,
               const float* __restrict__ q_w, const float* __restrict__ q_b,
               const float* __restrict__ k_w, const float* __restrict__ k_b,
               const float* __restrict__ v_w, const float* __restrict__ v_b,
               float* __restrict__ out)
{
  __shared__ __align__(16) unsigned char smem[153344];
  __hip_bfloat16* wfrag   = (__hip_bfloat16*)smem;        // 24576 bf16 elems
  float* stage            = (float*)smem;                  // fp32 staging (aliased)
  float* pos_lds          = (float*)(smem + 150528);       // 512 floats
  float* bias_lds         = (float*)(smem + 152576);       // 192 floats

  const int tid = threadIdx.x;
  const int bi  = blockIdx.x;
  const int b   = bi >> 10;
  const int hw0 = (bi & 1023) << 6;   // 64 pixels per block

  // ---------------- phase 0: stage biases, window pos-bias, weight fragments
  for (int i = tid; i < 192; i += 256) {
    float v;
    if (i < 64) v = q_b[i];
    else if (i < 128) v = k_b[i - 64];
    else v = v_b[i - 128];
    bias_lds[i] = v;
  }
  for (int idx = tid; idx < 512; idx += 256) {
    int uv = idx >> 7, k = idx & 127;
    float val = (k < 64) ? (float)(uv >> 1) : (float)(uv & 1);
    val *= 6.2831853071795864f / 1.000001f;        // 2*pi / (card(=1) + 1e-6)
    int i = k & 63, f = i >> 1;
    // dim_t = 10000^(f/32)  ->  inv = exp(-f * ln(10000)/32)
    float arg = val * __expf(-(float)f * 0.28782313662425572f);
    pos_lds[idx] = (i & 1) ? __cosf(arg) : __sinf(arg);
  }
  // weight fragments: wfrag[mat][ks*4+nt][lane][j] ; B layout: n=lane&15, k=quad*8+j
  for (int slot = tid; slot < 3072; slot += 256) {
    int mat    = slot >> 10;
    int rem    = slot & 1023;
    int ksnt   = rem >> 6;
    int lane_s = rem & 63;
    int ks = ksnt >> 2, nt = ksnt & 3;
    int n  = nt * 16 + (lane_s & 15);
    int k0 = ks * 32 + (lane_s >> 4) * 8;
    const float* wsrc = (mat == 0) ? q_w : (mat == 1) ? k_w : v_w;
    wsrc += n * PEPE + k0;
    __hip_bfloat16* dst = wfrag + slot * 8;
#pragma unroll
    for (int j = 0; j < 8; ++j) dst[j] = __float2bfloat16(wsrc[j]);
  }
  __syncthreads();

  const int lane = tid & 63;
  const int wv   = tid >> 6;
  const int quad = lane >> 4;
  const int l15  = lane & 15;

  // per-lane inverse dim_t table: f = (ks&1)*16 + quad*4 + jj
  float invd[2][4];
#pragma unroll
  for (int a = 0; a < 2; ++a)
#pragma unroll
    for (int jj = 0; jj < 4; ++jj)
      invd[a][jj] = __expf(-(float)(a * 16 + quad * 4 + jj) * 0.28782313662425572f);

  // ---------------- phase 1: Q fragments (A: m=lane&15 -> pixel, k=quad*8+j) + Q-GEMM
  const int qpix = hw0 + wv * 16 + l15;
  float fly = flow[(b * HWHW + qpix) * 2 + 1];
  float flx = flow[(b * HWHW + qpix) * 2 + 0];
  float gy = (float)(qpix >> 8) + fly;
  float gx = (float)(qpix & 255) + flx;
  float vy = (gy - floorf(gy)) * (6.2831853071795864f / 2.000001f);
  float vx = (gx - floorf(gx)) * (6.2831853071795864f / 2.000001f);

  short8 qa[4];
#pragma unroll
  for (int ks = 0; ks < 4; ++ks) {
    float val = (ks < 2) ? vy : vx;
#pragma unroll
    for (int jj = 0; jj < 4; ++jj) {
      int c = ks * 16 + quad * 4 + jj;
      float feat = feat_curr[(b * CC + c) * HWHW + qpix];
      float arg = val * invd[ks & 1][jj];
      qa[ks][jj * 2]     = f2bf(feat + __sinf(arg));   // even pe index -> sin
      qa[ks][jj * 2 + 1] = f2bf(feat + __cosf(arg));   // odd  pe index -> cos
    }
  }

  f32x4 qacc[4];
#pragma unroll
  for (int nt = 0; nt < 4; ++nt) qacc[nt] = (f32x4){0.f, 0.f, 0.f, 0.f};
#pragma unroll
  for (int ks = 0; ks < 4; ++ks) {
#pragma unroll
    for (int nt = 0; nt < 4; ++nt) {
      short8 bq = *(const short8*)(wfrag + ((0 * 16 + ks * 4 + nt) * 64 + lane) * 8);
      qacc[nt] = __builtin_amdgcn_mfma_f32_16x16x32_bf16(qa[ks], bq, qacc[nt], 0, 0, 0);
    }
  }

  // ---------------- phase 2: K/V fragments (rows = pixel*4 + uv) + fused K/V GEMM
  const int uv   = l15 & 3;
  const int prow = l15 >> 2;

  float pb[4][8];
#pragma unroll
  for (int ks = 0; ks < 4; ++ks)
#pragma unroll
    for (int j = 0; j < 8; ++j)
      pb[ks][j] = pos_lds[uv * 128 + ks * 32 + quad * 8 + j];

  float g[4][4][4];
#pragma unroll
  for (int mt = 0; mt < 4; ++mt) {
    int pix = hw0 + wv * 16 + mt * 4 + prow;
    float fy = flow[(b * HWHW + pix) * 2 + 1] + (float)(pix >> 8);
    float fx = flow[(b * HWHW + pix) * 2 + 0] + (float)(pix & 255);
    int gyi = (int)floorf(fy), gxi = (int)floorf(fx);
    int yy = min(max(gyi + (uv >> 1), 0), 255);
    int xx = min(max(gxi + (uv & 1), 0), 255);
    int lin = yy * 256 + xx;
#pragma unroll
    for (int ks = 0; ks < 4; ++ks)
#pragma unroll
      for (int jj = 0; jj < 4; ++jj) {
        int c = ks * 16 + quad * 4 + jj;
        g[mt][ks][jj] = feat_supp[(b * CC + c) * HWHW + lin];
      }
  }

  short8 ka[4][4];
#pragma unroll
  for (int mt = 0; mt < 4; ++mt)
#pragma unroll
    for (int ks = 0; ks < 4; ++ks)
#pragma unroll
      for (int jj = 0; jj < 4; ++jj) {
        ka[mt][ks][jj * 2]     = f2bf(g[mt][ks][jj] + pb[ks][jj * 2]);
        ka[mt][ks][jj * 2 + 1] = f2bf(g[mt][ks][jj] + pb[ks][jj * 2 + 1]);
      }

  f32x4 kacc[4][4], vacc[4][4];
#pragma unroll
  for (int mt = 0; mt < 4; ++mt)
#pragma unroll
    for (int nt = 0; nt < 4; ++nt) {
      kacc[mt][nt] = (f32x4){0.f, 0.f, 0.f, 0.f};
      vacc[mt][nt] = (f32x4){0.f, 0.f, 0.f, 0.f};
    }
#pragma unroll
  for (int ks = 0; ks < 4; ++ks) {
    short8 bk[4], bv[4];
#pragma unroll
    for (int nt = 0; nt < 4; ++nt) {
      bk[nt] = *(const short8*)(wfrag + ((16 + ks * 4 + nt) * 64 + lane) * 8);
      bv[nt] = *(const short8*)(wfrag + ((32 + ks * 4 + nt) * 64 + lane) * 8);
    }
#pragma unroll
    for (int mt = 0; mt < 4; ++mt)
#pragma unroll
      for (int nt = 0; nt < 4; ++nt) {
        kacc[mt][nt] = __builtin_amdgcn_mfma_f32_16x16x32_bf16(ka[mt][ks], bk[nt], kacc[mt][nt], 0, 0, 0);
        vacc[mt][nt] = __builtin_amdgcn_mfma_f32_16x16x32_bf16(ka[mt][ks], bv[nt], vacc[mt][nt], 0, 0, 0);
      }
  }

  __syncthreads();   // all waves done reading wfrag; safe to alias with staging

  // ---------------- phase 3: stage q/k/v (fp32, +bias) into LDS
  // q_s: stride 68 floats/pixel ; k_s/v_s: stride 260 floats/pixel (4*64 + 4 pad)
  float* q_sf = stage;                  // 64*68   = 4352 floats
  float* k_sf = stage + 4352;           // 64*260  = 16640 floats
  float* v_sf = stage + 4352 + 16640;

#pragma unroll
  for (int nt = 0; nt < 4; ++nt) {
    int c = nt * 16 + l15;
    float bq = bias_lds[c], bk_ = bias_lds[64 + c], bv_ = bias_lds[128 + c];
#pragma unroll
    for (int r = 0; r < 4; ++r) {
      int pl = wv * 16 + quad * 4 + r;                 // D: row = quad*4 + reg
      q_sf[pl * 68 + c] = qacc[nt][r] + bq;
    }
#pragma unroll
    for (int mt = 0; mt < 4; ++mt) {
      int pl = wv * 16 + mt * 4 + quad;                // row = pix*4+uv ; uv = reg
#pragma unroll
      for (int r = 0; r < 4; ++r) {
        k_sf[pl * 260 + r * 64 + c] = kacc[mt][nt][r] + bk_;
        v_sf[pl * 260 + r * 64 + c] = vacc[mt][nt][r] + bv_;
      }
    }
  }
  __syncthreads();

  // ---------------- phase 4: per-pixel attention epilogue
  const int p   = tid >> 2;        // local pixel 0..63
  const int sub = tid & 3;         // 2 heads per thread
  const int hw  = hw0 + p;
#pragma unroll
  for (int hh = 0; hh < 2; ++hh) {
    int h = sub * 2 + hh;
    f32x4 q0 = *(const f32x4*)(q_sf + p * 68 + h * 8);
    f32x4 q1 = *(const f32x4*)(q_sf + p * 68 + h * 8 + 4);
    float logit[4];
    float vvb[4][8];
#pragma unroll
    for (int u = 0; u < 4; ++u) {
      f32x4 k0 = *(const f32x4*)(k_sf + p * 260 + u * 64 + h * 8);
      f32x4 k1 = *(const f32x4*)(k_sf + p * 260 + u * 64 + h * 8 + 4);
      f32x4 v0 = *(const f32x4*)(v_sf + p * 260 + u * 64 + h * 8);
      f32x4 v1 = *(const f32x4*)(v_sf + p * 260 + u * 64 + h * 8 + 4);
      float s = q0.x * k0.x + q0.y * k0.y + q0.z * k0.z + q0.w * k0.w
              + q1.x * k1.x + q1.y * k1.y + q1.z * k1.z + q1.w * k1.w;
      logit[u] = s * 0.35355339059327373f;
      vvb[u][0] = v0.x; vvb[u][1] = v0.y; vvb[u][2] = v0.z; vvb[u][3] = v0.w;
      vvb[u][4] = v1.x; vvb[u][5] = v1.y; vvb[u][6] = v1.z; vvb[u][7] = v1.w;
    }
    float mx = fmaxf(fmaxf(logit[0], logit[1]), fmaxf(logit[2], logit[3]));
    float e0 = __expf(logit[0] - mx), e1 = __expf(logit[1] - mx);
    float e2 = __expf(logit[2] - mx), e3 = __expf(logit[3] - mx);
    float inv = 1.0f / (e0 + e1 + e2 + e3);
    float a0 = e0 * inv, a1 = e1 * inv, a2 = e2 * inv, a3 = e3 * inv;
#pragma unroll
    for (int d = 0; d < 8; ++d) {
      float o = a0 * vvb[0][d] + a1 * vvb[1][d] + a2 * vvb[2][d] + a3 * vvb[3][d];
      out[(b * CC + h * 8 + d) * HWHW + hw] = o;
    }
  }
}

extern "C" void kernel_launch(void* const* d_in, const int* in_sizes, int n_in,
                              void* d_out, int out_size, void* d_ws, size_t ws_size,
                              hipStream_t stream) {
  const float* feat_supp = (const float*)d_in[0];
  const float* flow      = (const float*)d_in[1];
  const float* feat_curr = (const float*)d_in[2];
  const float* q_w = (const float*)d_in[3];
  const float* q_b = (const float*)d_in[4];
  const float* k_w = (const float*)d_in[5];
  const float* k_b = (const float*)d_in[6];
  const float* v_w = (const float*)d_in[7];
  const float* v_b = (const float*)d_in[8];
  float* out = (float*)d_out;
  (void)in_sizes; (void)n_in; (void)out_size; (void)d_ws; (void)ws_size;
  dim3 grid(2048), block(256);
  hipLaunchKernelGGL(iw_kernel, grid, block, 0, stream,
                     feat_supp, flow, feat_curr, q_w, q_b, k_w, k_b, v_w, v_b, out);
}